// Round 13
// baseline (211.320 us; speedup 1.0000x reference)
//
#include <hip/hip_runtime.h>
#include <hip/hip_cooperative_groups.h>
#include <hip/hip_bf16.h>
#include <math.h>

namespace cg = cooperative_groups;

// Dtype model (pinned R0-R4): float inputs f32; edge_index int32; d_out read
// as f32: chunk0 = pred f32[0:393216], chunk1 = yg f32[393216:786432]; np
// reference computed from bf16-cast inputs -> bf16 intermediates safe.
//
// R7: spills kill. R9: strided us8 LDS reads = bank conflicts. R10: dense-P
// MFMA aggregation. R11 (best, 118.6us): 2-layer gat fused @512thr.
// R12 FAILED: 1024thr gat regressed (+2.6us) -> per-phase latency is NOT the
// limiter; ~55us of the window is launch/dispatch machinery (3 launches).
// R13 (this): ONE cooperative launch (256 blocks x 512 thr = 1 block/CU):
// phase P (pack + yg) -> grid.sync -> phase G (R11 gat verbatim) ->
// grid.sync -> phase M (mlp rebalanced for 8 waves). LDS phases share a union.

#define N_NODES 16384
#define B_GRAPHS 256
#define K_NODES 64
#define DEG 8
#define NHEADS 4
#define C1 100
#define C2 128
#define IN_F 96
#define HID 64
#define OUT_SZ 24
#define PRED_ELEMS (K_NODES * B_GRAPHS * OUT_SZ)   // 393216

#define W1T_ROWS 448
#define W1T_K    96
#define W2T_ROWS 512
#define W2T_K    128

#define P1N (W1T_ROWS * W1T_K)        // 43008
#define P2N (W2T_ROWS * W2T_K)        // 65536
#define F1N (K_NODES * HID * C2)      // 524288 : fw1t[k][j*128+i]
#define F2N (K_NODES * 32 * HID)      // 131072 : fw2t[k][q*64+j], q padded 32
#define YG4 (PRED_ELEMS / 4)          // 98304
#define PREPN (P1N + P2N + F1N + F2N + YG4)   // 862208

using bf16 = __hip_bfloat16;
typedef __attribute__((ext_vector_type(8))) short          frag_ab;
typedef __attribute__((ext_vector_type(4))) float          frag_cd;
typedef unsigned short us8 __attribute__((ext_vector_type(8)));
typedef unsigned short us4 __attribute__((ext_vector_type(4)));

__device__ __forceinline__ float us2f(unsigned short u) {
  return __bfloat162float(__ushort_as_bfloat16(u));
}
__device__ __forceinline__ short f2bf_s(float f) {
  return __builtin_bit_cast(short, __float2bfloat16(f));
}

// LDS layouts for the two heavy phases, overlaid.
struct SmGat {                         // ~137.5 KB
  short          As[64 * 136];         // A slab (L1 stride 104, L2 stride 136)
  unsigned short xs[512 * 72];         // xl^T
  short          Ps[NHEADS * 64 * 72]; // dense attention P
  float avs1[400], avd1[400], avs2[512], avd2[512];
  float bia1[C1], bia2[C2];
  int   edg[K_NODES * DEG];
  float als[64 * 5], ald[64 * 5];
};
struct SmMlp {                         // ~48 KB
  short As[64 * 136];
  short B1[HID * 136];
  short Hs[64 * 72];
  short B2[32 * 72];
  float b1s[HID], b2s[32];
};
union SmAll { SmGat g; SmMlp m; };

__global__ __launch_bounds__(512)
void fused_all(const float* __restrict__ x, const int* __restrict__ ei,
               const float* __restrict__ y,
               const float* __restrict__ W1, const float* __restrict__ as1,
               const float* __restrict__ ad1, const float* __restrict__ b1,
               const float* __restrict__ W2, const float* __restrict__ as2,
               const float* __restrict__ ad2, const float* __restrict__ b2,
               const float* __restrict__ fw1, const float* __restrict__ fb1,
               const float* __restrict__ fw2, const float* __restrict__ fb2,
               bf16* __restrict__ ws, float* __restrict__ out) {
  __shared__ __align__(16) SmAll sm;
  cg::grid_group grid = cg::this_grid();

  const int t  = threadIdx.x;
  const int wv = t >> 6;
  const int l  = t & 63;
  const int lm = l & 15;
  const int lk = (l >> 4) * 8;
  const int rq = (l >> 4) * 4;

  // workspace carve-up
  bf16* h2   = ws;
  bf16* W1t  = h2 + (size_t)N_NODES * C2;
  bf16* W2t  = W1t + P1N;
  bf16* fw1t = W2t + P2N;
  bf16* fw2t = fw1t + F1N;
  float* yg  = out + PRED_ELEMS;

  // ================= phase P: pack weights + yg =================
  for (int idx = blockIdx.x * 512 + t; idx < PREPN; idx += 256 * 512) {
    if (idx < P1N) {
      int c = idx / W1T_K, k = idx - c * W1T_K;
      W1t[idx] = __float2bfloat16((c < 400) ? W1[(size_t)k * 400 + c] : 0.f);
    } else if (idx < P1N + P2N) {
      int i2 = idx - P1N;
      int c = i2 >> 7, k = i2 & 127;
      W2t[i2] = __float2bfloat16((k < 100) ? W2[(size_t)k * 512 + c] : 0.f);
    } else if (idx < P1N + P2N + F1N) {
      int i2 = idx - P1N - P2N;
      int k = i2 >> 13, r = i2 & 8191, j = r >> 7, i = r & 127;
      fw1t[i2] = __float2bfloat16(fw1[(size_t)k * 8192 + i * 64 + j]);
    } else if (idx < P1N + P2N + F1N + F2N) {
      int i2 = idx - P1N - P2N - F1N;
      int k = i2 >> 11, r = i2 & 2047, q = r >> 6, j = r & 63;
      fw2t[i2] = __float2bfloat16((q < OUT_SZ) ? fw2[(size_t)k * 1536 + j * 24 + q] : 0.f);
    } else {
      int j = idx - P1N - P2N - F1N - F2N;
      int i = j * 4;
      float4 v = *(const float4*)(y + i);
      v.x = __bfloat162float(__float2bfloat16(v.x));
      v.y = __bfloat162float(__float2bfloat16(v.y));
      v.z = __bfloat162float(__float2bfloat16(v.z));
      v.w = __bfloat162float(__float2bfloat16(v.w));
      *(float4*)(yg + i) = v;
    }
  }
  grid.sync();

  // ================= phase G: two-layer GAT (R11 body, 512 thr) ============
  {
    constexpr int LDA1 = IN_F + 8;   // 104
    constexpr int LDA2 = 136;
    constexpr int LDT  = 72;
    auto& S = sm.g;
    const int g = blockIdx.x;

    // ---- stage ----
    {
      constexpr int QR = IN_F / 4;
      for (int idx = t; idx < 64 * QR; idx += 512) {
        int m = idx / QR, q = idx - m * QR;
        const float4 v = *(const float4*)(x + ((size_t)(g * 64 + m) * IN_F + q * 4));
        short* d = &S.As[m * LDA1 + q * 4];
        d[0] = f2bf_s(v.x); d[1] = f2bf_s(v.y); d[2] = f2bf_s(v.z); d[3] = f2bf_s(v.w);
      }
    }
    for (int idx = t; idx < 400; idx += 512) { S.avs1[idx] = as1[idx]; S.avd1[idx] = ad1[idx]; }
    { S.avs2[t] = as2[t]; S.avd2[t] = ad2[t]; }
    if (t < C1) S.bia1[t] = b1[t];
    if (t < C2) S.bia2[t] = b2[t];
    S.edg[t] = ei[g * K_NODES * DEG + t] & (K_NODES - 1);
    for (int idx = t; idx < NHEADS * 64 * LDT / 8; idx += 512)
      *(us8*)&S.Ps[idx * 8] = (us8)0;
    __syncthreads();

    // ---- L1 GEMM: xl1 = As @ W1t -> xs^T (waves 0-6, chunk each) ----
    if (wv < 7) {
      const int n0 = wv * 64;
      frag_cd acc[4][4] = {};
#pragma unroll
      for (int ks = 0; ks < IN_F; ks += 32) {
        frag_ab b[4];
#pragma unroll
        for (int nt = 0; nt < 4; ++nt)
          b[nt] = *(const frag_ab*)((const short*)W1t +
                                    (size_t)(n0 + nt * 16 + lm) * W1T_K + ks + lk);
#pragma unroll
        for (int mt = 0; mt < 4; ++mt) {
          frag_ab a = *(const frag_ab*)&S.As[(mt * 16 + lm) * LDA1 + ks + lk];
#pragma unroll
          for (int nt = 0; nt < 4; ++nt)
            acc[mt][nt] = __builtin_amdgcn_mfma_f32_16x16x32_bf16(a, b[nt],
                                                                  acc[mt][nt], 0, 0, 0);
        }
      }
#pragma unroll
      for (int mt = 0; mt < 4; ++mt)
#pragma unroll
        for (int nt = 0; nt < 4; ++nt) {
          const int c4 = n0 + nt * 16 + lm;
          us4 o;
#pragma unroll
          for (int r = 0; r < 4; ++r) o[r] = (unsigned short)f2bf_s(acc[mt][nt][r]);
          *(us4*)&S.xs[c4 * LDT + mt * 16 + rq] = o;
        }
    }
    __syncthreads();

    // ---- L1 logits ----
    if (t < 256) {
      const int n = t >> 2, h = t & 3;
      float ss = 0.f, sd = 0.f;
#pragma unroll 4
      for (int c = 0; c < C1; ++c) {
        const float v = us2f(S.xs[(h * C1 + c) * LDT + n]);
        ss += v * S.avs1[h * C1 + c];
        sd += v * S.avd1[h * C1 + c];
      }
      S.als[n * 5 + h] = ss;
      S.ald[n * 5 + h] = sd;
    }
    __syncthreads();

    // ---- L1 softmax -> Ps; spare threads zero As2 k-pads ----
    if (t < 256) {
      const int n = t >> 2, h = t & 3;
      const float ad = S.ald[n * 5 + h];
      int   sv[9];
      float a[9];
#pragma unroll
      for (int j = 0; j < 8; ++j) sv[j] = S.edg[n * DEG + j];
      sv[8] = n;
#pragma unroll
      for (int j = 0; j < 9; ++j) {
        float v = S.als[sv[j] * 5 + h] + ad;
        a[j] = (v >= 0.f) ? v : 0.2f * v;
      }
      float m = -1e30f;
#pragma unroll
      for (int j = 0; j < 9; ++j) m = fmaxf(m, a[j]);
      float s = 0.f;
#pragma unroll
      for (int j = 0; j < 9; ++j) { a[j] = __expf(a[j] - m); s += a[j]; }
      const float inv = 1.f / (s + 1e-16f);
      short* prow = &S.Ps[(h * 64 + n) * LDT];
#pragma unroll
      for (int j = 0; j < 9; ++j) {
        float tw = a[j];
#pragma unroll
        for (int i = 0; i < 9; ++i)
          if (i != j && sv[i] == sv[j]) tw += a[i];
        prow[sv[j]] = f2bf_s(tw * inv);
      }
    } else {
      for (int i = t - 256; i < 64 * 28; i += 256) {
        int m = i / 28, kk = 100 + (i - m * 28);
        S.As[m * LDA2 + kk] = 0;
      }
    }
    __syncthreads();

    // ---- L1 agg -> As2 (stride 136), ELU ----
    {
      const int mw = (wv & 3) * 16;
      const int cgi = wv >> 2;
      const int ntb = cgi * 4;
      const int nte = (cgi == 0) ? 4 : 7;
      frag_cd acc[4] = {};
#pragma unroll
      for (int h = 0; h < NHEADS; ++h)
#pragma unroll
        for (int ks = 0; ks < 64; ks += 32) {
          frag_ab a = *(const frag_ab*)&S.Ps[(h * 64 + mw + lm) * LDT + ks + lk];
          for (int nt = ntb; nt < nte; ++nt) {
            frag_ab b = *(const frag_ab*)&S.xs[(h * C1 + nt * 16 + lm) * LDT + ks + lk];
            acc[nt - ntb] = __builtin_amdgcn_mfma_f32_16x16x32_bf16(a, b,
                                                                    acc[nt - ntb], 0, 0, 0);
          }
        }
      for (int nt = ntb; nt < nte; ++nt) {
        const int c = nt * 16 + lm;
        if (c < C1) {
          const float bc = S.bia1[c];
#pragma unroll
          for (int r = 0; r < 4; ++r) {
            float vv = acc[nt - ntb][r] * 0.25f + bc;
            vv = (vv > 0.f) ? vv : (__expf(vv) - 1.f);
            S.As[(mw + rq + r) * LDA2 + c] = f2bf_s(vv);
          }
        }
      }
    }
    __syncthreads();

    // ---- L2 GEMM: xl2 = As @ W2t -> xs^T (8 waves, chunk each) ----
    {
      const int n0 = wv * 64;
      frag_cd acc[4][4] = {};
#pragma unroll
      for (int ks = 0; ks < 128; ks += 32) {
        frag_ab b[4];
#pragma unroll
        for (int nt = 0; nt < 4; ++nt)
          b[nt] = *(const frag_ab*)((const short*)W2t +
                                    (size_t)(n0 + nt * 16 + lm) * W2T_K + ks + lk);
#pragma unroll
        for (int mt = 0; mt < 4; ++mt) {
          frag_ab a = *(const frag_ab*)&S.As[(mt * 16 + lm) * LDA2 + ks + lk];
#pragma unroll
          for (int nt = 0; nt < 4; ++nt)
            acc[mt][nt] = __builtin_amdgcn_mfma_f32_16x16x32_bf16(a, b[nt],
                                                                  acc[mt][nt], 0, 0, 0);
        }
      }
#pragma unroll
      for (int mt = 0; mt < 4; ++mt)
#pragma unroll
        for (int nt = 0; nt < 4; ++nt) {
          const int c4 = n0 + nt * 16 + lm;
          us4 o;
#pragma unroll
          for (int r = 0; r < 4; ++r) o[r] = (unsigned short)f2bf_s(acc[mt][nt][r]);
          *(us4*)&S.xs[c4 * LDT + mt * 16 + rq] = o;
        }
    }
    __syncthreads();

    // ---- L2 logits ----
    if (t < 256) {
      const int n = t >> 2, h = t & 3;
      float ss = 0.f, sd = 0.f;
#pragma unroll 4
      for (int c = 0; c < C2; ++c) {
        const float v = us2f(S.xs[(h * C2 + c) * LDT + n]);
        ss += v * S.avs2[h * C2 + c];
        sd += v * S.avd2[h * C2 + c];
      }
      S.als[n * 5 + h] = ss;
      S.ald[n * 5 + h] = sd;
    }
    __syncthreads();

    // ---- L2 softmax -> Ps (same support; no re-zero) ----
    if (t < 256) {
      const int n = t >> 2, h = t & 3;
      const float ad = S.ald[n * 5 + h];
      int   sv[9];
      float a[9];
#pragma unroll
      for (int j = 0; j < 8; ++j) sv[j] = S.edg[n * DEG + j];
      sv[8] = n;
#pragma unroll
      for (int j = 0; j < 9; ++j) {
        float v = S.als[sv[j] * 5 + h] + ad;
        a[j] = (v >= 0.f) ? v : 0.2f * v;
      }
      float m = -1e30f;
#pragma unroll
      for (int j = 0; j < 9; ++j) m = fmaxf(m, a[j]);
      float s = 0.f;
#pragma unroll
      for (int j = 0; j < 9; ++j) { a[j] = __expf(a[j] - m); s += a[j]; }
      const float inv = 1.f / (s + 1e-16f);
      short* prow = &S.Ps[(h * 64 + n) * LDT];
#pragma unroll
      for (int j = 0; j < 9; ++j) {
        float tw = a[j];
#pragma unroll
        for (int i = 0; i < 9; ++i)
          if (i != j && sv[i] == sv[j]) tw += a[i];
        prow[sv[j]] = f2bf_s(tw * inv);
      }
    }
    __syncthreads();

    // ---- L2 agg -> h2 global ----
    {
      const int mw = (wv & 3) * 16;
      const int cgi = wv >> 2;
      const int ntb = cgi * 4;
      frag_cd acc[4] = {};
#pragma unroll
      for (int h = 0; h < NHEADS; ++h)
#pragma unroll
        for (int ks = 0; ks < 64; ks += 32) {
          frag_ab a = *(const frag_ab*)&S.Ps[(h * 64 + mw + lm) * LDT + ks + lk];
#pragma unroll
          for (int nt = 0; nt < 4; ++nt) {
            frag_ab b = *(const frag_ab*)&S.xs[(h * C2 + (ntb + nt) * 16 + lm) * LDT + ks + lk];
            acc[nt] = __builtin_amdgcn_mfma_f32_16x16x32_bf16(a, b, acc[nt], 0, 0, 0);
          }
        }
      unsigned short* outp = (unsigned short*)h2 + (size_t)(g * 64) * C2;
#pragma unroll
      for (int nt = 0; nt < 4; ++nt) {
        const int c = (ntb + nt) * 16 + lm;
        const float bc = S.bia2[c];
#pragma unroll
        for (int r = 0; r < 4; ++r) {
          float vv = acc[nt][r] * 0.25f + bc;
          outp[(size_t)(mw + rq + r) * C2 + c] = (unsigned short)f2bf_s(vv);
        }
      }
    }
  }
  grid.sync();

  // ================= phase M: MLP head (8 waves) =================
  {
    constexpr int LDA = 136;
    constexpr int LDH = 72;
    auto& M = sm.m;
    const int k  = blockIdx.x & 63;
    const int ms = blockIdx.x >> 6;

    for (int idx = t; idx < 64 * 16; idx += 512) {
      int r = idx >> 4, o = idx & 15;
      const us8 v = *(const us8*)((const unsigned short*)h2 +
          ((size_t)((ms * 64 + r) * K_NODES + k) * C2) + o * 8);
      *(us8*)&M.As[r * LDA + o * 8] = v;
    }
    for (int idx = t; idx < HID * 16; idx += 512) {
      int n = idx >> 4, o = idx & 15;
      *(us8*)&M.B1[n * LDA + o * 8] =
          *(const us8*)((const unsigned short*)fw1t + (size_t)k * 8192 + n * 128 + o * 8);
    }
    for (int idx = t; idx < 32 * 8; idx += 512) {
      int q = idx >> 3, o = idx & 7;
      *(us8*)&M.B2[q * LDH + o * 8] =
          *(const us8*)((const unsigned short*)fw2t + (size_t)k * 2048 + q * 64 + o * 8);
    }
    if (t < HID) M.b1s[t] = fb1[k * HID + t];
    if (t >= 64 && t < 96) M.b2s[t - 64] = (t - 64 < OUT_SZ) ? fb2[k * OUT_SZ + (t - 64)] : 0.f;
    __syncthreads();

    // GEMM1: wave = (row-half mh, ntile nt1): 2 mt x 1 nt, K=128
    {
      const int mh  = (wv >> 2) * 32;
      const int nt1 = wv & 3;
      frag_cd acc[2] = {};
#pragma unroll
      for (int ks = 0; ks < C2; ks += 32) {
        frag_ab b = *(const frag_ab*)&M.B1[(nt1 * 16 + lm) * LDA + ks + lk];
#pragma unroll
        for (int mt = 0; mt < 2; ++mt) {
          frag_ab a = *(const frag_ab*)&M.As[(mh + mt * 16 + lm) * LDA + ks + lk];
          acc[mt] = __builtin_amdgcn_mfma_f32_16x16x32_bf16(a, b, acc[mt], 0, 0, 0);
        }
      }
      const int j  = nt1 * 16 + lm;
      const float bj = M.b1s[j];
#pragma unroll
      for (int mt = 0; mt < 2; ++mt)
#pragma unroll
        for (int r = 0; r < 4; ++r)
          M.Hs[(mh + mt * 16 + rq + r) * LDH + j] = f2bf_s(fmaxf(acc[mt][r] + bj, 0.f));
    }
    __syncthreads();

    // GEMM2: wave = (row-quarter mq, ntile nt2): 1 mt x 1 nt, K=64
    {
      const int mq  = (wv >> 1) * 16;
      const int nt2 = wv & 1;
      frag_cd acc = {};
#pragma unroll
      for (int ks = 0; ks < HID; ks += 32) {
        frag_ab a = *(const frag_ab*)&M.Hs[(mq + lm) * LDH + ks + lk];
        frag_ab b = *(const frag_ab*)&M.B2[(nt2 * 16 + lm) * LDH + ks + lk];
        acc = __builtin_amdgcn_mfma_f32_16x16x32_bf16(a, b, acc, 0, 0, 0);
      }
      const int q = nt2 * 16 + lm;
      if (q < OUT_SZ) {
        const float bq = M.b2s[q];
#pragma unroll
        for (int r = 0; r < 4; ++r)
          out[((size_t)k * B_GRAPHS + ms * 64 + mq + rq + r) * OUT_SZ + q] = acc[r] + bq;
      }
    }
  }
}

// ---------------------------------------------------------------------------
extern "C" void kernel_launch(void* const* d_in, const int* in_sizes, int n_in,
                              void* d_out, int out_size, void* d_ws, size_t ws_size,
                              hipStream_t stream) {
  const float* x   = (const float*)d_in[0];
  const int*   ei  = (const int*)d_in[1];
  const float* y   = (const float*)d_in[3];
  const float* W1  = (const float*)d_in[4];
  const float* as1 = (const float*)d_in[5];
  const float* ad1 = (const float*)d_in[6];
  const float* b1  = (const float*)d_in[7];
  const float* W2  = (const float*)d_in[8];
  const float* as2 = (const float*)d_in[9];
  const float* ad2 = (const float*)d_in[10];
  const float* b2  = (const float*)d_in[11];
  const float* fw1 = (const float*)d_in[12];
  const float* fb1 = (const float*)d_in[13];
  const float* fw2 = (const float*)d_in[14];
  const float* fb2 = (const float*)d_in[15];

  bf16*  ws  = (bf16*)d_ws;
  float* out = (float*)d_out;

  void* args[] = {(void*)&x,  (void*)&ei,  (void*)&y,
                  (void*)&W1, (void*)&as1, (void*)&ad1, (void*)&b1,
                  (void*)&W2, (void*)&as2, (void*)&ad2, (void*)&b2,
                  (void*)&fw1,(void*)&fb1, (void*)&fw2, (void*)&fb2,
                  (void*)&ws, (void*)&out};
  hipLaunchCooperativeKernel((const void*)fused_all, dim3(B_GRAPHS), dim3(512),
                             args, 0, stream);
}

// Round 14
// 123.082 us; speedup vs baseline: 1.7169x; 1.7169x over previous
//
#include <hip/hip_runtime.h>
#include <hip/hip_bf16.h>
#include <math.h>

// Dtype model (pinned R0-R4): float inputs f32; edge_index int32; d_out read
// as f32: chunk0 = pred f32[0:393216], chunk1 = yg f32[393216:786432]; np
// reference computed from bf16-cast inputs -> bf16 intermediates safe.
//
// R7: spills kill. R9: strided LDS reads = bank conflicts. R10: dense-P MFMA
// agg. R11 (118.6us, best): 2-layer gat @512thr, 3 launches. R12 FAILED:
// 1024thr gat (+2.6). R13 FAILED: cooperative grid.sync costs >> launch
// boundaries (103us kernel). R14 (this): back to 3 launches; gat barriers
// 9 -> 5 via (a) logits = A@(W@a) with wa precomputed in prep -> logits fold
// into GEMM phases; (b) in-wave softmax->agg (agg only needs own 16 nodes'
// P rows). mlp: ms split 8 -> grid 512 = 2 blocks/CU.

#define N_NODES 16384
#define B_GRAPHS 256
#define K_NODES 64
#define DEG 8
#define NHEADS 4
#define C1 100
#define C2 128
#define IN_F 96
#define HID 64
#define OUT_SZ 24
#define PRED_ELEMS (K_NODES * B_GRAPHS * OUT_SZ)   // 393216

#define W1T_ROWS 448
#define W1T_K    96
#define W2T_ROWS 512
#define W2T_K    128

#define P1N (W1T_ROWS * W1T_K)        // 43008
#define P2N (W2T_ROWS * W2T_K)        // 65536
#define F1N (K_NODES * HID * C2)      // 524288 : fw1t[k][j*128+i]
#define F2N (K_NODES * 32 * HID)      // 131072 : fw2t[k][q*64+j], q pad 32
#define YG4 (PRED_ELEMS / 4)          // 98304
#define WAN (768 + 1024)              // wa1 (96*4*2) + wa2 (128*4*2) dots
#define PREPN (P1N + P2N + F1N + F2N + YG4 + WAN)

using bf16 = __hip_bfloat16;
typedef __attribute__((ext_vector_type(8))) short          frag_ab;
typedef __attribute__((ext_vector_type(4))) float          frag_cd;
typedef unsigned short us8 __attribute__((ext_vector_type(8)));
typedef unsigned short us4 __attribute__((ext_vector_type(4)));

__device__ __forceinline__ float us2f(unsigned short u) {
  return __bfloat162float(__ushort_as_bfloat16(u));
}
__device__ __forceinline__ short f2bf_s(float f) {
  return __builtin_bit_cast(short, __float2bfloat16(f));
}

// ---------------------------------------------------------------------------
// prep: pack W1t/W2t/fw1t/fw2t (bf16) + yg + wa vectors (f32 GEMVs).
// wa1[k][h] = sum_c W1[k, h*100+c] * a1[h,c]   (k<96)
// wa2[k][h] = sum_c W2[k, h*128+c] * a2[h,c]   (k<100; zero-padded to 128)
// ---------------------------------------------------------------------------
__global__ __launch_bounds__(256)
void prep(const float* __restrict__ W1, const float* __restrict__ W2,
          const float* __restrict__ fw1, const float* __restrict__ fw2,
          const float* __restrict__ y,
          const float* __restrict__ as1, const float* __restrict__ ad1,
          const float* __restrict__ as2, const float* __restrict__ ad2,
          bf16* __restrict__ W1t, bf16* __restrict__ W2t,
          bf16* __restrict__ fw1t, bf16* __restrict__ fw2t,
          float* __restrict__ yg,
          float* __restrict__ wa1s, float* __restrict__ wa1d,
          float* __restrict__ wa2s, float* __restrict__ wa2d) {
  int idx = blockIdx.x * 256 + threadIdx.x;
  if (idx < P1N) {
    int c = idx / W1T_K, k = idx - c * W1T_K;
    W1t[idx] = __float2bfloat16((c < 400) ? W1[(size_t)k * 400 + c] : 0.f);
  } else if (idx < P1N + P2N) {
    int i2 = idx - P1N;
    int c = i2 >> 7, k = i2 & 127;
    W2t[i2] = __float2bfloat16((k < 100) ? W2[(size_t)k * 512 + c] : 0.f);
  } else if (idx < P1N + P2N + F1N) {
    int i2 = idx - P1N - P2N;
    int k = i2 >> 13, r = i2 & 8191, j = r >> 7, i = r & 127;
    fw1t[i2] = __float2bfloat16(fw1[(size_t)k * 8192 + i * 64 + j]);
  } else if (idx < P1N + P2N + F1N + F2N) {
    int i2 = idx - P1N - P2N - F1N;
    int k = i2 >> 11, r = i2 & 2047, q = r >> 6, j = r & 63;
    fw2t[i2] = __float2bfloat16((q < OUT_SZ) ? fw2[(size_t)k * 1536 + j * 24 + q] : 0.f);
  } else if (idx < P1N + P2N + F1N + F2N + YG4) {
    int j = idx - P1N - P2N - F1N - F2N;
    int i = j * 4;
    float4 v = *(const float4*)(y + i);
    v.x = __bfloat162float(__float2bfloat16(v.x));
    v.y = __bfloat162float(__float2bfloat16(v.y));
    v.z = __bfloat162float(__float2bfloat16(v.z));
    v.w = __bfloat162float(__float2bfloat16(v.w));
    *(float4*)(yg + i) = v;
  } else {
    int tw = idx - P1N - P2N - F1N - F2N - YG4;
    if (tw < 768) {                    // wa1: 96 k x 4 h x 2 (s/d)
      int k = tw >> 3, h = (tw >> 1) & 3, sd = tw & 1;
      const float* a = sd ? ad1 : as1;
      float s = 0.f;
      for (int c = 0; c < C1; ++c)
        s += W1[(size_t)k * 400 + h * C1 + c] * a[h * C1 + c];
      (sd ? wa1d : wa1s)[k * 4 + h] = s;
    } else if (tw < WAN) {             // wa2: 128 k x 4 h x 2
      int t2 = tw - 768;
      int k = t2 >> 3, h = (t2 >> 1) & 3, sd = t2 & 1;
      float s = 0.f;
      if (k < 100) {
        const float* a = sd ? ad2 : as2;
        for (int c = 0; c < C2; ++c)
          s += W2[(size_t)k * 512 + h * C2 + c] * a[h * C2 + c];
      }
      (sd ? wa2d : wa2s)[k * 4 + h] = s;
    }
  }
}

// ---------------------------------------------------------------------------
// Fused two-layer GAT, one block per graph (grid=256), 512 threads.
// Barriers: stage | L1 GEMM+logits | L1 softmax+agg+padzero | L2 GEMM+logits
// | L2 softmax+agg -> global write. (5 phases, 4 internal barriers.)
// ---------------------------------------------------------------------------
__global__ __launch_bounds__(512)
void gat_fused(const float* __restrict__ x,
               const bf16* __restrict__ W1t, const bf16* __restrict__ W2t,
               const int* __restrict__ esrc,
               const float* __restrict__ wa1s_g, const float* __restrict__ wa1d_g,
               const float* __restrict__ wa2s_g, const float* __restrict__ wa2d_g,
               const float* __restrict__ b1, const float* __restrict__ b2,
               bf16* __restrict__ h2out) {
  constexpr int LDA1 = IN_F + 8;   // 104 shorts
  constexpr int LDA2 = 136;
  constexpr int LDT  = 72;

  __shared__ __align__(16) short          As[64 * LDA2];          // 17.4 KB
  __shared__ __align__(16) unsigned short xs[512 * LDT];          // 73.7 KB
  __shared__ __align__(16) short          Ps[NHEADS * 64 * LDT];  // 36.9 KB
  __shared__ float wa1s[384], wa1d[384], wa2s[512], wa2d[512];    // 7.2 KB
  __shared__ float bia1[C1], bia2[C2];
  __shared__ int   edg[K_NODES * DEG];
  __shared__ float als[64 * 5], ald[64 * 5];

  const int g = blockIdx.x;
  const int t = threadIdx.x;
  const int wv = t >> 6;
  const int l  = t & 63;
  const int lm = l & 15;
  const int lk = (l >> 4) * 8;
  const int rq = (l >> 4) * 4;

  // ================= phase 0: stage =================
  {
    constexpr int QR = IN_F / 4;
    for (int idx = t; idx < 64 * QR; idx += 512) {
      int m = idx / QR, q = idx - m * QR;
      const float4 v = *(const float4*)(x + ((size_t)(g * 64 + m) * IN_F + q * 4));
      short* d = &As[m * LDA1 + q * 4];
      d[0] = f2bf_s(v.x); d[1] = f2bf_s(v.y); d[2] = f2bf_s(v.z); d[3] = f2bf_s(v.w);
    }
  }
  if (t < 384) { wa1s[t] = wa1s_g[t]; wa1d[t] = wa1d_g[t]; }
  { wa2s[t] = wa2s_g[t]; wa2d[t] = wa2d_g[t]; }
  if (t < C1) bia1[t] = b1[t];
  if (t >= 128 && t < 128 + C2) bia2[t - 128] = b2[t - 128];
  edg[t] = esrc[g * K_NODES * DEG + t] & (K_NODES - 1);
  for (int idx = t; idx < NHEADS * 64 * LDT / 8; idx += 512)
    *(us8*)&Ps[idx * 8] = (us8)0;
  __syncthreads();

  // ========== L1: GEMM (waves 0-6) || logits (wave 7) ==========
  if (wv < 7) {
    const int n0 = wv * 64;
    frag_cd acc[4][4] = {};
#pragma unroll
    for (int ks = 0; ks < IN_F; ks += 32) {
      frag_ab b[4];
#pragma unroll
      for (int nt = 0; nt < 4; ++nt)
        b[nt] = *(const frag_ab*)((const short*)W1t +
                                  (size_t)(n0 + nt * 16 + lm) * W1T_K + ks + lk);
#pragma unroll
      for (int mt = 0; mt < 4; ++mt) {
        frag_ab a = *(const frag_ab*)&As[(mt * 16 + lm) * LDA1 + ks + lk];
#pragma unroll
        for (int nt = 0; nt < 4; ++nt)
          acc[mt][nt] = __builtin_amdgcn_mfma_f32_16x16x32_bf16(a, b[nt],
                                                                acc[mt][nt], 0, 0, 0);
      }
    }
#pragma unroll
    for (int mt = 0; mt < 4; ++mt)
#pragma unroll
      for (int nt = 0; nt < 4; ++nt) {
        const int c4 = n0 + nt * 16 + lm;
        us4 o;
#pragma unroll
        for (int r = 0; r < 4; ++r) o[r] = (unsigned short)f2bf_s(acc[mt][nt][r]);
        *(us4*)&xs[c4 * LDT + mt * 16 + rq] = o;
      }
  } else {
    // logits: lane = node; als/ald[n][h] = sum_k As[n][k] * wa1[k][h]
    const int n = l;
    float ss[4] = {}, dd[4] = {};
#pragma unroll
    for (int o = 0; o < IN_F / 8; ++o) {
      const us8 v = *(const us8*)&((const unsigned short*)As)[n * LDA1 + o * 8];
#pragma unroll
      for (int j = 0; j < 8; ++j) {
        const float f = us2f(v[j]);
        const int k4 = (o * 8 + j) * 4;
#pragma unroll
        for (int h = 0; h < 4; ++h) {
          ss[h] += f * wa1s[k4 + h];
          dd[h] += f * wa1d[k4 + h];
        }
      }
    }
#pragma unroll
    for (int h = 0; h < 4; ++h) { als[n * 5 + h] = ss[h]; ald[n * 5 + h] = dd[h]; }
  }
  __syncthreads();

  // ========== L1: in-wave softmax -> Ps, then agg -> As2 (+ padzero) ======
  {
    const int mw = (wv & 3) * 16;
    // softmax for this wave's 16 nodes x 4 heads (pair waves duplicate)
    {
      const int n = mw + (l >> 2), h = l & 3;
      const float ad = ald[n * 5 + h];
      int   sv[9];
      float a[9];
#pragma unroll
      for (int j = 0; j < 8; ++j) sv[j] = edg[n * DEG + j];
      sv[8] = n;
#pragma unroll
      for (int j = 0; j < 9; ++j) {
        float v = als[sv[j] * 5 + h] + ad;
        a[j] = (v >= 0.f) ? v : 0.2f * v;     // leaky_relu 0.2
      }
      float m = -1e30f;
#pragma unroll
      for (int j = 0; j < 9; ++j) m = fmaxf(m, a[j]);
      float s = 0.f;
#pragma unroll
      for (int j = 0; j < 9; ++j) { a[j] = __expf(a[j] - m); s += a[j]; }
      const float inv = 1.f / (s + 1e-16f);
      short* prow = &Ps[(h * 64 + n) * LDT];
#pragma unroll
      for (int j = 0; j < 9; ++j) {
        float tw = a[j];
#pragma unroll
        for (int i = 0; i < 9; ++i)
          if (i != j && sv[i] == sv[j]) tw += a[i];
        prow[sv[j]] = f2bf_s(tw * inv);       // idempotent dedupe
      }
    }
    // waves 4-7: zero As2 k-padding (cols 100..127; disjoint from agg writes)
    if (wv >= 4) {
      for (int i = (wv - 4) * 64 + l; i < 64 * 28; i += 256) {
        int m = i / 28, kk = 100 + (i - m * 28);
        As[m * LDA2 + kk] = 0;
      }
    }
    // agg: h1 rows mw..mw+16 (reads only own-written P rows)
    const int cgi = wv >> 2;
    const int ntb = cgi * 4;
    const int nte = (cgi == 0) ? 4 : 7;       // NT=7 split 4+3
    frag_cd acc[4] = {};
#pragma unroll
    for (int h = 0; h < NHEADS; ++h)
#pragma unroll
      for (int ks = 0; ks < 64; ks += 32) {
        frag_ab a = *(const frag_ab*)&Ps[(h * 64 + mw + lm) * LDT + ks + lk];
        for (int nt = ntb; nt < nte; ++nt) {
          frag_ab b = *(const frag_ab*)&xs[(h * C1 + nt * 16 + lm) * LDT + ks + lk];
          acc[nt - ntb] = __builtin_amdgcn_mfma_f32_16x16x32_bf16(a, b,
                                                                  acc[nt - ntb], 0, 0, 0);
        }
      }
    for (int nt = ntb; nt < nte; ++nt) {
      const int c = nt * 16 + lm;
      if (c < C1) {
        const float bc = bia1[c];
#pragma unroll
        for (int r = 0; r < 4; ++r) {
          float vv = acc[nt - ntb][r] * 0.25f + bc;
          vv = (vv > 0.f) ? vv : (__expf(vv) - 1.f);   // ELU
          As[(mw + rq + r) * LDA2 + c] = f2bf_s(vv);
        }
      }
    }
  }
  __syncthreads();

  // ========== L2: GEMM (all 8 waves) + distributed logits ==========
  {
    const int n0 = wv * 64;
    frag_cd acc[4][4] = {};
#pragma unroll
    for (int ks = 0; ks < 128; ks += 32) {
      frag_ab b[4];
#pragma unroll
      for (int nt = 0; nt < 4; ++nt)
        b[nt] = *(const frag_ab*)((const short*)W2t +
                                  (size_t)(n0 + nt * 16 + lm) * W2T_K + ks + lk);
#pragma unroll
      for (int mt = 0; mt < 4; ++mt) {
        frag_ab a = *(const frag_ab*)&As[(mt * 16 + lm) * LDA2 + ks + lk];
#pragma unroll
        for (int nt = 0; nt < 4; ++nt)
          acc[mt][nt] = __builtin_amdgcn_mfma_f32_16x16x32_bf16(a, b[nt],
                                                                acc[mt][nt], 0, 0, 0);
      }
    }
#pragma unroll
    for (int mt = 0; mt < 4; ++mt)
#pragma unroll
      for (int nt = 0; nt < 4; ++nt) {
        const int c4 = n0 + nt * 16 + lm;
        us4 o;
#pragma unroll
        for (int r = 0; r < 4; ++r) o[r] = (unsigned short)f2bf_s(acc[mt][nt][r]);
        *(us4*)&xs[c4 * LDT + mt * 16 + rq] = o;
      }
    // logits2 from As2 (h1): wave handles 8 nodes; lane = (n_loc, h, s/d)
    const int n  = wv * 8 + (l >> 3);
    const int h  = (l >> 1) & 3;
    const int sd = l & 1;
    const float* wa = sd ? wa2d : wa2s;
    float s = 0.f;
#pragma unroll
    for (int o = 0; o < 16; ++o) {            // K padded to 128; pads zero
      const us8 v = *(const us8*)&((const unsigned short*)As)[n * LDA2 + o * 8];
#pragma unroll
      for (int j = 0; j < 8; ++j)
        s += us2f(v[j]) * wa[(o * 8 + j) * 4 + h];
    }
    if (sd) ald[n * 5 + h] = s; else als[n * 5 + h] = s;
  }
  __syncthreads();

  // ========== L2: in-wave softmax -> Ps (same support), agg -> global ======
  {
    const int mw = (wv & 3) * 16;
    {
      const int n = mw + (l >> 2), h = l & 3;
      const float ad = ald[n * 5 + h];
      int   sv[9];
      float a[9];
#pragma unroll
      for (int j = 0; j < 8; ++j) sv[j] = edg[n * DEG + j];
      sv[8] = n;
#pragma unroll
      for (int j = 0; j < 9; ++j) {
        float v = als[sv[j] * 5 + h] + ad;
        a[j] = (v >= 0.f) ? v : 0.2f * v;
      }
      float m = -1e30f;
#pragma unroll
      for (int j = 0; j < 9; ++j) m = fmaxf(m, a[j]);
      float s = 0.f;
#pragma unroll
      for (int j = 0; j < 9; ++j) { a[j] = __expf(a[j] - m); s += a[j]; }
      const float inv = 1.f / (s + 1e-16f);
      short* prow = &Ps[(h * 64 + n) * LDT];
#pragma unroll
      for (int j = 0; j < 9; ++j) {
        float tw = a[j];
#pragma unroll
        for (int i = 0; i < 9; ++i)
          if (i != j && sv[i] == sv[j]) tw += a[i];
        prow[sv[j]] = f2bf_s(tw * inv);
      }
    }
    const int cgi = wv >> 2;
    const int ntb = cgi * 4;                  // NT=8 split 4+4
    frag_cd acc[4] = {};
#pragma unroll
    for (int h = 0; h < NHEADS; ++h)
#pragma unroll
      for (int ks = 0; ks < 64; ks += 32) {
        frag_ab a = *(const frag_ab*)&Ps[(h * 64 + mw + lm) * LDT + ks + lk];
#pragma unroll
        for (int nt = 0; nt < 4; ++nt) {
          frag_ab b = *(const frag_ab*)&xs[(h * C2 + (ntb + nt) * 16 + lm) * LDT + ks + lk];
          acc[nt] = __builtin_amdgcn_mfma_f32_16x16x32_bf16(a, b, acc[nt], 0, 0, 0);
        }
      }
    unsigned short* outp = (unsigned short*)h2out + (size_t)(g * 64) * C2;
#pragma unroll
    for (int nt = 0; nt < 4; ++nt) {
      const int c = (ntb + nt) * 16 + lm;
      const float bc = bia2[c];
#pragma unroll
      for (int r = 0; r < 4; ++r) {
        float vv = acc[nt][r] * 0.25f + bc;
        outp[(size_t)(mw + rq + r) * C2 + c] = (unsigned short)f2bf_s(vv);
      }
    }
  }
}

// ---------------------------------------------------------------------------
// MFMA MLP head. Grid 512 = (k in [0,64)) x (ms in [0,8)): 32 rows/block,
// 2 blocks/CU for staging/compute overlap.
// ---------------------------------------------------------------------------
__global__ __launch_bounds__(256)
void mlp_mfma(const bf16* __restrict__ h2,
              const bf16* __restrict__ fw1t, const float* __restrict__ fb1,
              const bf16* __restrict__ fw2t, const float* __restrict__ fb2,
              float* __restrict__ pred) {
  constexpr int LDA = 136;
  constexpr int LDH = 72;
  __shared__ __align__(16) short As[32 * LDA];
  __shared__ __align__(16) short B1[HID * LDA];
  __shared__ __align__(16) short Hs[32 * LDH];
  __shared__ __align__(16) short B2[32 * LDH];
  __shared__ float b1s[HID];
  __shared__ float b2s[32];

  const int k  = blockIdx.x & 63;
  const int ms = blockIdx.x >> 6;            // [0,8)
  const int t  = threadIdx.x;

  for (int idx = t; idx < 32 * 16; idx += 256) {
    int r = idx >> 4, o = idx & 15;
    const us8 v = *(const us8*)((const unsigned short*)h2 +
        ((size_t)((ms * 32 + r) * K_NODES + k) * C2) + o * 8);
    *(us8*)&As[r * LDA + o * 8] = v;
  }
  for (int idx = t; idx < HID * 16; idx += 256) {
    int n = idx >> 4, o = idx & 15;
    *(us8*)&B1[n * LDA + o * 8] =
        *(const us8*)((const unsigned short*)fw1t + (size_t)k * 8192 + n * 128 + o * 8);
  }
  for (int idx = t; idx < 32 * 8; idx += 256) {
    int q = idx >> 3, o = idx & 7;
    *(us8*)&B2[q * LDH + o * 8] =
        *(const us8*)((const unsigned short*)fw2t + (size_t)k * 2048 + q * 64 + o * 8);
  }
  if (t < HID) b1s[t] = fb1[k * HID + t];
  if (t >= 64 && t < 96) b2s[t - 64] = (t - 64 < OUT_SZ) ? fb2[k * OUT_SZ + (t - 64)] : 0.f;
  __syncthreads();

  const int wv = t >> 6;
  const int l  = t & 63;
  const int lm = l & 15;
  const int lk = (l >> 4) * 8;
  const int rq = (l >> 4) * 4;

  // GEMM1: 2 row-tiles x 4 col-tiles over 4 waves: wave = (mt = wv&1, ntp = wv>>1)
  {
    const int mt  = wv & 1;
    const int ntp = wv >> 1;
    frag_cd acc[2] = {};
#pragma unroll
    for (int ks = 0; ks < C2; ks += 32) {
      frag_ab a = *(const frag_ab*)&As[(mt * 16 + lm) * LDA + ks + lk];
#pragma unroll
      for (int u = 0; u < 2; ++u) {
        frag_ab b = *(const frag_ab*)&B1[((ntp * 2 + u) * 16 + lm) * LDA + ks + lk];
        acc[u] = __builtin_amdgcn_mfma_f32_16x16x32_bf16(a, b, acc[u], 0, 0, 0);
      }
    }
#pragma unroll
    for (int u = 0; u < 2; ++u) {
      const int j  = (ntp * 2 + u) * 16 + lm;
      const float bj = b1s[j];
#pragma unroll
      for (int r = 0; r < 4; ++r)
        Hs[(mt * 16 + rq + r) * LDH + j] = f2bf_s(fmaxf(acc[u][r] + bj, 0.f));
    }
  }
  __syncthreads();

  // GEMM2: 2 row-tiles x 2 col-tiles over 4 waves: wave = (mt = wv>>1, nt = wv&1)
  {
    const int mt = wv >> 1;
    const int nt = wv & 1;
    frag_cd acc = {};
#pragma unroll
    for (int ks = 0; ks < HID; ks += 32) {
      frag_ab a = *(const frag_ab*)&Hs[(mt * 16 + lm) * LDH + ks + lk];
      frag_ab b = *(const frag_ab*)&B2[(nt * 16 + lm) * LDH + ks + lk];
      acc = __builtin_amdgcn_mfma_f32_16x16x32_bf16(a, b, acc, 0, 0, 0);
    }
    const int q = nt * 16 + lm;
    if (q < OUT_SZ) {
      const float bq = b2s[q];
#pragma unroll
      for (int r = 0; r < 4; ++r)
        pred[((size_t)k * B_GRAPHS + ms * 32 + mt * 16 + rq + r) * OUT_SZ + q] = acc[r] + bq;
    }
  }
}

// ---------------------------------------------------------------------------
extern "C" void kernel_launch(void* const* d_in, const int* in_sizes, int n_in,
                              void* d_out, int out_size, void* d_ws, size_t ws_size,
                              hipStream_t stream) {
  const float* x   = (const float*)d_in[0];
  const int*   ei  = (const int*)d_in[1];    // [2,E]: first E entries = src
  const float* y   = (const float*)d_in[3];
  const float* W1  = (const float*)d_in[4];
  const float* as1 = (const float*)d_in[5];
  const float* ad1 = (const float*)d_in[6];
  const float* b1  = (const float*)d_in[7];
  const float* W2  = (const float*)d_in[8];
  const float* as2 = (const float*)d_in[9];
  const float* ad2 = (const float*)d_in[10];
  const float* b2  = (const float*)d_in[11];
  const float* fw1 = (const float*)d_in[12];
  const float* fb1 = (const float*)d_in[13];
  const float* fw2 = (const float*)d_in[14];
  const float* fb2 = (const float*)d_in[15];

  // Workspace (~5.7 MB): h2, W1t, W2t, fw1t, fw2t, wa vectors
  bf16* h2    = (bf16*)d_ws;
  bf16* W1t   = h2 + (size_t)N_NODES * C2;
  bf16* W2t   = W1t + P1N;
  bf16* fw1t  = W2t + P2N;
  bf16* fw2t  = fw1t + F1N;
  float* wa1s = (float*)(fw2t + F2N);
  float* wa1d = wa1s + 384;
  float* wa2s = wa1d + 384;
  float* wa2d = wa2s + 512;

  float* out = (float*)d_out;

  prep<<<(PREPN + 255) / 256, 256, 0, stream>>>(
      W1, W2, fw1, fw2, y, as1, ad1, as2, ad2,
      W1t, W2t, fw1t, fw2t, out + PRED_ELEMS, wa1s, wa1d, wa2s, wa2d);

  gat_fused<<<B_GRAPHS, 512, 0, stream>>>(x, W1t, W2t, ei,
                                          wa1s, wa1d, wa2s, wa2d, b1, b2, h2);

  mlp_mfma<<<K_NODES * 8, 256, 0, stream>>>(h2, fw1t, fb1, fw2t, fb2, out);
}